// Round 7
// baseline (7081.109 us; speedup 1.0000x reference)
//
#include <hip/hip_runtime.h>
#include <stdint.h>

typedef unsigned short u16;
typedef unsigned int   u32;
typedef unsigned long long u64;
typedef _Float16 half8 __attribute__((ext_vector_type(8)));
typedef __attribute__((ext_vector_type(4))) float f32x4;

#define DEV static __device__ __forceinline__

DEV float bf2f(u16 u){ union{u32 i; float f;} v; v.i=((u32)u)<<16; return v.f; }
DEV u16 f2bf(float f){ u32 x=__float_as_uint(f); return (u16)((x + 0x7FFFu + ((x>>16)&1u))>>16); }
DEV u16 f2hu(float f){ _Float16 h = (_Float16)f; return *(u16*)&h; }
DEV float hu2f(u16 u){ _Float16 h = *(_Float16*)&u; return (float)h; }
DEV float sigm(float x){ return 1.0f/(1.0f+__expf(-x)); }
DEV float tanhr(float x){ float a=fabsf(x); float e=__expf(-2.0f*a); float t=(1.0f-e)/(1.0f+e); return x<0.0f? -t:t; }

typedef const __attribute__((address_space(1))) u32 gu32;
typedef __attribute__((address_space(3))) u32 lu32;
DEV void gload16(const void* g, void* l){
  __builtin_amdgcn_global_load_lds((gu32*)g, (lu32*)l, 16, 0, 0);
}
// coherent 4B store (write-through to coherence point), fire-and-forget
DEV void gstore4c(void* p, u32 v){
  asm volatile("global_store_dword %0, %1, off sc0 sc1" : : "v"(p), "v"(v) : "memory");
}

DEV u16 ld_h(const void* p, size_t i, int isbf){
  float f = isbf ? bf2f(((const u16*)p)[i]) : ((const float*)p)[i];
  return f2hu(f);
}

// -------- dtype detector: bf16 exponent-band statistics --------
__global__ void detect_dtype(const void* emb, u32* flag)
{
  const u16* p = (const u16*)emb;
  int i = threadIdx.x;
  u32 e0 = (p[i]    >> 7) & 0xFF;
  u32 e1 = (p[i+64] >> 7) & 0xFF;
  unsigned long long b0 = __ballot(e0 >= 0x60 && e0 <= 0x7E);
  unsigned long long b1 = __ballot(e1 >= 0x60 && e1 <= 0x7E);
  if (i == 0) *flag = (__popcll(b0) + __popcll(b1) > 96) ? 1u : 0u;
}

// -------- emb table -> fp16 (512x256) --------
__global__ __launch_bounds__(256) void embconv(const void* __restrict__ emb, u16* __restrict__ embH,
                                               const u32* __restrict__ flag)
{
  const int isbf = *flag;
  int i = blockIdx.x*256 + threadIdx.x;
  embH[i] = ld_h(emb, i, isbf);
}

// ------------- weight transpose (+ gate interleave): out[n'][k] = fp16(in[k][n]) -------------
__global__ __launch_bounds__(256) void transpose_bt(const void* __restrict__ in,
                                                    u16* __restrict__ out,
                                                    int K, int N, int perm,
                                                    const u32* __restrict__ flag)
{
  const int isbf = *flag;
  __shared__ u16 t[32][33];
  int nb = blockIdx.x*32, kb = blockIdx.y*32;
  int tx = threadIdx.x & 31, ty = threadIdx.x >> 5;   // 32 x 8
  #pragma unroll
  for (int i=0;i<4;++i){
    int kl = ty + i*8;
    t[kl][tx] = ld_h(in, (size_t)(kb+kl)*N + nb + tx, isbf);
  }
  __syncthreads();
  #pragma unroll
  for (int i=0;i<4;++i){
    int nl = ty + i*8;
    int n = nb + nl;
    int np = perm ? ((n & 511)*4 + (n >> 9)) : n;
    out[(size_t)np*K + kb + tx] = t[tx][nl];
  }
}

__global__ __launch_bounds__(256) void bias_prep(const void* __restrict__ in, float* __restrict__ out,
                                                 int N, int perm, const u32* __restrict__ flag)
{
  const int isbf = *flag;
  int n = blockIdx.x*256 + threadIdx.x;
  if (n < N){
    int np = perm ? ((n & 511)*4 + (n >> 9)) : n;
    out[np] = isbf ? bf2f(((const u16*)in)[n]) : ((const float*)in)[n];
  }
}

// ---------------- batched chunk GEMM (swapped operands): Zq[lt][u'][b] = packed 4-gate quads ----------------
// z=0: A gathered from embH via tokens (K=256). z=1,2: A = xo_prev chunk (K=512).
__global__ __launch_bounds__(256) void gemm3(
    const u16* __restrict__ A1, const u16* __restrict__ A2,
    const u16* __restrict__ BT0, const u16* __restrict__ BT1, const u16* __restrict__ BT2,
    const float* __restrict__ b0p, const float* __restrict__ b1p, const float* __restrict__ b2p,
    u16* __restrict__ C0, u16* __restrict__ C1, u16* __restrict__ C2,
    const int* __restrict__ tok, const u16* __restrict__ embH, int t0g,
    int act0, int act1, int act2)
{
  const int z = blockIdx.z;
  if (z==0 && !act0) return;
  if (z==1 && !act1) return;
  if (z==2 && !act2) return;
  const int K = (z==0) ? 256 : 512;
  const u16* BT = z==0?BT0 : z==1?BT1 : BT2;
  const float* bias = z==0?b0p : z==1?b1p : b2p;
  u16* C = z==0?C0 : z==1?C1 : C2;

  __shared__ u16 As[128*32];
  __shared__ u16 Bs[128*32];
  const int tid = threadIdx.x, lane = tid & 63, wid = tid >> 6;
  const int wr = wid >> 1, wc = wid & 1;
  const int m0 = blockIdx.x*128, n0 = blockIdx.y*128;
  const int r  = tid >> 2;
  const int ce = (tid & 3)*8;
  const u16 *a0, *a1;
  if (z == 0){
    int r0 = m0 + r;     int tt = t0g + (r0>>6); int bb = r0 & 63;
    a0 = embH + (size_t)tok[bb*1024 + tt]*256 + ce;
    int r1 = m0 + 64 + r; tt = t0g + (r1>>6); bb = r1 & 63;
    a1 = embH + (size_t)tok[bb*1024 + tt]*256 + ce;
  } else {
    const u16* A = (z==1) ? A1 : A2;
    a0 = A + (size_t)(m0 + r)*512 + ce;
    a1 = A + (size_t)(m0 + 64 + r)*512 + ce;
  }
  const u16* bp0 = BT + (size_t)(n0 + r)*K + ce;
  const u16* bp1 = BT + (size_t)(n0 + 64 + r)*K + ce;
  char* asw0 = (char*)As + (wid<<10);
  char* asw1 = (char*)As + 4096 + (wid<<10);
  char* bsw0 = (char*)Bs + (wid<<10);
  char* bsw1 = (char*)Bs + 4096 + (wid<<10);

  f32x4 acc[4][4];
  #pragma unroll
  for (int i=0;i<4;++i)
    #pragma unroll
    for (int j=0;j<4;++j) acc[i][j] = (f32x4){0.f,0.f,0.f,0.f};

  const int koff = (lane>>4)*8;
  for (int k0 = 0; k0 < K; k0 += 32){
    __syncthreads();
    gload16(a0 + k0, asw0);
    gload16(a1 + k0, asw1);
    gload16(bp0 + k0, bsw0);
    gload16(bp1 + k0, bsw1);
    __syncthreads();
    half8 af[4], bf[4];
    #pragma unroll
    for (int mt=0;mt<4;++mt) af[mt] = *(const half8*)(As + (wr*64 + mt*16 + (lane&15))*32 + koff);
    #pragma unroll
    for (int nt=0;nt<4;++nt) bf[nt] = *(const half8*)(Bs + (wc*64 + nt*16 + (lane&15))*32 + koff);
    // swapped: D rows = n' (register dim j -> gate), D cols = m (lane dim)
    #pragma unroll
    for (int mt=0;mt<4;++mt)
      #pragma unroll
      for (int nt=0;nt<4;++nt)
        acc[mt][nt] = __builtin_amdgcn_mfma_f32_16x16x32_f16(bf[nt], af[mt], acc[mt][nt], 0,0,0);
  }
  #pragma unroll
  for (int mt=0;mt<4;++mt){
    int m = m0 + wr*64 + mt*16 + (lane&15);
    int ltl = m >> 6, b = m & 63;
    #pragma unroll
    for (int nt=0;nt<4;++nt){
      int u = ((n0 + wc*64 + nt*16) >> 2) + (lane>>4);
      float4 bq = *(const float4*)(bias + u*4);
      u16 qo[4];
      qo[0] = f2hu(acc[mt][nt][0] + bq.x);
      qo[1] = f2hu(acc[mt][nt][1] + bq.y);
      qo[2] = f2hu(acc[mt][nt][2] + bq.z);
      qo[3] = f2hu(acc[mt][nt][3] + bq.w);
      ((uint2*)C)[(size_t)(ltl*512 + u)*64 + b] = *(uint2*)qo;
    }
  }
}

// ---------------- final logits GEMM (K=512, output permute t-major -> (B,T), dtype per flag) --------
__global__ __launch_bounds__(256) void gemm_bt(const u16* __restrict__ A, const u16* __restrict__ BT,
                                               const float* __restrict__ bias, void* __restrict__ C,
                                               int M, int N, int K, const u32* __restrict__ flag)
{
  __shared__ u16 As[128*32];
  __shared__ u16 Bs[128*32];
  const int tid = threadIdx.x, lane = tid & 63, wid = tid >> 6;
  const int wr = wid >> 1, wc = wid & 1;
  const int m0 = blockIdx.x*128, n0 = blockIdx.y*128;
  const int r  = tid >> 2;
  const int ce = (tid & 3)*8;
  const u16* a0 = A  + (size_t)(m0 + r)*K + ce;
  const u16* a1 = A  + (size_t)(m0 + 64 + r)*K + ce;
  const u16* b0 = BT + (size_t)(n0 + r)*K + ce;
  const u16* b1 = BT + (size_t)(n0 + 64 + r)*K + ce;
  char* asw0 = (char*)As + (wid<<10);
  char* asw1 = (char*)As + 4096 + (wid<<10);
  char* bsw0 = (char*)Bs + (wid<<10);
  char* bsw1 = (char*)Bs + 4096 + (wid<<10);

  f32x4 acc[4][4];
  #pragma unroll
  for (int i=0;i<4;++i)
    #pragma unroll
    for (int j=0;j<4;++j) acc[i][j] = (f32x4){0.f,0.f,0.f,0.f};

  const int koff = (lane>>4)*8;
  for (int k0 = 0; k0 < K; k0 += 32){
    __syncthreads();
    gload16(a0 + k0, asw0);
    gload16(a1 + k0, asw1);
    gload16(b0 + k0, bsw0);
    gload16(b1 + k0, bsw1);
    __syncthreads();
    half8 af[4], bf[4];
    #pragma unroll
    for (int mt=0;mt<4;++mt) af[mt] = *(const half8*)(As + (wr*64 + mt*16 + (lane&15))*32 + koff);
    #pragma unroll
    for (int nt=0;nt<4;++nt) bf[nt] = *(const half8*)(Bs + (wc*64 + nt*16 + (lane&15))*32 + koff);
    #pragma unroll
    for (int mt=0;mt<4;++mt)
      #pragma unroll
      for (int nt=0;nt<4;++nt)
        acc[mt][nt] = __builtin_amdgcn_mfma_f32_16x16x32_f16(af[mt], bf[nt], acc[mt][nt], 0,0,0);
  }
  const int wrf32 = (*flag == 0);
  #pragma unroll
  for (int mt=0;mt<4;++mt){
    #pragma unroll
    for (int nt=0;nt<4;++nt){
      int col = n0 + wc*64 + nt*16 + (lane&15);
      float bv = bias[col];
      #pragma unroll
      for (int j=0;j<4;++j){
        int row = m0 + wr*64 + mt*16 + ((lane>>4)<<2) + j;
        int orow = ((row & 63) << 10) | (row >> 6);
        float v = acc[mt][nt][j] + bv;
        if (wrf32) ((float*)C)[(size_t)orow*N + col] = v;
        else       ((u16*)C)[(size_t)orow*N + col] = f2bf(v);
      }
    }
  }
}

// ---------------- fused recurrence: 192 WGs x 512 threads = 3 layers x (4 bgroups x 16 u-WGs) ----------------
// Tag-embedded H sync (see r6). This round: 8 waves/WG so per-thread Wr = 64 VGPR (held in regs),
// one-shot poll pass (4x dwordx4 + vmcnt in ONE asm block), double-buffered LDS (1 barrier/step).
__global__ __launch_bounds__(512,2) void lstm3(
    const uint2* __restrict__ Zq0, const uint2* __restrict__ Zq1, const uint2* __restrict__ Zq2,
    const u16* __restrict__ Wr0T, const u16* __restrict__ Wr1T, const u16* __restrict__ Wr2T,
    const int* __restrict__ lengths,
    u16* __restrict__ xo0, u16* __restrict__ xo1, u16* __restrict__ xf,
    u32* Hbase, float* Cbase, int d)
{
  __shared__ char Hs[2][16384];       // 16 rows x 1KB fp16 each, 16B-block XOR swizzle
  const int tid = threadIdx.x, lane = tid & 63, w = tid >> 6;    // w in [0,8)
  const int layer = blockIdx.x >> 6;
  const int sub = blockIdx.x & 63;
  const int g = sub >> 4, i = sub & 15;
  const int c = d - layer;
  if (c < 0 || c > 15) return;
  const int t0 = c * 64;

  const uint2* Zq = layer==0?Zq0 : layer==1?Zq1 : Zq2;
  const u16* WrT  = layer==0?Wr0T : layer==1?Wr1T : Wr2T;
  u32* Hb0 = Hbase + (size_t)layer*65536;    // 2 bufs x [64][512] u32
  u32* Hb1 = Hb0 + 32768;
  float* Cg = Cbase + (size_t)layer*32768;

  const int q = lane >> 4, r15 = lane & 15, rsw = r15 & 7;
  const int bglob = g*16 + r15;
  const int mylen = lengths[bglob];
  const int u0 = i*32 + w*4 + q;             // this thread's single u

  // Wr fragment -> registers (64 VGPR): row = gate-col i*128 + w*16 + r15, k-slice q*8
  half8 wreg[16];
  {
    const u16* wsrc = WrT + (size_t)(i*128 + w*16 + r15)*512 + q*8;
    #pragma unroll
    for (int kk=0; kk<16; ++kk)
      wreg[kk] = *(const half8*)(wsrc + kk*32);
  }
  float c0 = Cg[bglob*512 + u0];

  // poll/stage geometry: 2 chunks per thread; chunk = 8 tagged u32 = 32B (16B fp16 payload)
  const int ch0 = tid*2, ch1 = tid*2 + 1;    // 1024 chunks = 16 rows x 64
  const int row0 = ch0 >> 6, blk0 = ch0 & 63;
  const int row1 = ch1 >> 6, blk1 = ch1 & 63;
  const int so0 = row0*1024 + ((blk0 ^ (row0 & 7))<<4);
  const int so1 = row1*1024 + ((blk1 ^ (row1 & 7))<<4);

  for (int lt = 0; lt < 64; ++lt){
    const int t = t0 + lt;
    u32* Hcur = (t & 1) ? Hb1 : Hb0;
    u32* Hnxt = (t & 1) ? Hb0 : Hb1;
    char* Hsb = Hs[lt & 1];

    // Zx gate quad (plain cached load, written by a previous dispatch's gemm3)
    uint2 zqa = Zq[(size_t)(lt*512 + u0)*64 + bglob];

    // ---- one-shot poll pass: both chunks, 4x dwordx4 + vmcnt in one asm block ----
    {
      const u32 tg = (u32)t;
      const u32* p0 = Hcur + (size_t)(g*16 + row0)*512 + blk0*8;
      const u32* p1 = Hcur + (size_t)(g*16 + row1)*512 + blk1*8;
      u32 pend = 3;
      do {
        uint4 va, vb, vc, vd;
        asm volatile(
          "global_load_dwordx4 %0, %4, off sc0 sc1\n\t"
          "global_load_dwordx4 %1, %5, off sc0 sc1\n\t"
          "global_load_dwordx4 %2, %6, off sc0 sc1\n\t"
          "global_load_dwordx4 %3, %7, off sc0 sc1\n\t"
          "s_waitcnt vmcnt(0)"
          : "=&v"(va), "=&v"(vb), "=&v"(vc), "=&v"(vd)
          : "v"(p0), "v"((const u32*)(p0+4)), "v"(p1), "v"((const u32*)(p1+4))
          : "memory");
        if (pend & 1u){
          bool ok = (va.x>>16)==tg && (va.y>>16)==tg && (va.z>>16)==tg && (va.w>>16)==tg
                 && (vb.x>>16)==tg && (vb.y>>16)==tg && (vb.z>>16)==tg && (vb.w>>16)==tg;
          if (ok){
            uint4 o;
            o.x = (va.x&0xFFFFu)|(va.y<<16); o.y = (va.z&0xFFFFu)|(va.w<<16);
            o.z = (vb.x&0xFFFFu)|(vb.y<<16); o.w = (vb.z&0xFFFFu)|(vb.w<<16);
            *(uint4*)(Hsb + so0) = o;
            pend &= ~1u;
          }
        }
        if (pend & 2u){
          bool ok = (vc.x>>16)==tg && (vc.y>>16)==tg && (vc.z>>16)==tg && (vc.w>>16)==tg
                 && (vd.x>>16)==tg && (vd.y>>16)==tg && (vd.z>>16)==tg && (vd.w>>16)==tg;
          if (ok){
            uint4 o;
            o.x = (vc.x&0xFFFFu)|(vc.y<<16); o.y = (vc.z&0xFFFFu)|(vc.w<<16);
            o.z = (vd.x&0xFFFFu)|(vd.y<<16); o.w = (vd.z&0xFFFFu)|(vd.w<<16);
            *(uint4*)(Hsb + so1) = o;
            pend &= ~2u;
          }
        }
        if (pend) __builtin_amdgcn_s_sleep(1);
      } while (pend);
    }
    __syncthreads();

    // ---- Z^T = Wr-frag (regs) x H (LDS): single MFMA chain, acc regs = 4 gates of (b,u0) ----
    f32x4 acc = {0.f,0.f,0.f,0.f};
    #pragma unroll
    for (int kk=0;kk<16;++kk){
      half8 hf = *(const half8*)(Hsb + r15*1024 + (((kk*4 + q) ^ rsw)<<4));
      acc = __builtin_amdgcn_mfma_f32_16x16x32_f16(wreg[kk], hf, acc, 0,0,0);
    }

    // ---- gates fully in-register ----
    const bool live = t < mylen;
    float zi = hu2f((u16)zqa.x)        + acc[0];
    float zf = hu2f((u16)(zqa.x>>16))  + acc[1];
    float zg = hu2f((u16)zqa.y)        + acc[2];
    float zo = hu2f((u16)(zqa.y>>16))  + acc[3];
    float ii = sigm(zi), ff = sigm(zf), gg = tanhr(zg), oo = sigm(zo);
    float cn = ff*c0 + ii*gg;
    float hn = oo*tanhr(cn);
    c0 = live ? cn : c0;
    int ub = u0*2;
    float hold = hu2f(*(const u16*)(Hsb + r15*1024 + (((ub>>4) ^ rsw)<<4) + (ub & 15)));
    u16 hst = f2hu(live ? hn : hold);
    u16 xv  = f2hu(live ? hn : 0.f);

    // tagged h store: fire-and-forget, then xout store
    gstore4c(Hnxt + (size_t)bglob*512 + u0, (((u32)(t+1))<<16) | (u32)hst);
    if (layer == 2)
      xf[((size_t)t*64 + bglob)*512 + u0] = xv;
    else {
      u16* xo = layer ? xo1 : xo0;
      xo[((size_t)lt*64 + bglob)*512 + u0] = xv;
    }
    // no trailing barrier: next step stages into the other LDS buffer
  }
  Cg[bglob*512 + u0] = c0;
}

// ---------------------------------- host ----------------------------------
extern "C" void kernel_launch(void* const* d_in, const int* in_sizes, int n_in,
                              void* d_out, int out_size, void* d_ws, size_t ws_size,
                              hipStream_t stream)
{
  const int* tokens  = (const int*)d_in[0];
  const int* lengths = (const int*)d_in[1];
  const void* emb    = d_in[2];
  const void* Wk[3] = {d_in[3], d_in[6], d_in[9]};
  const void* Wr[3] = {d_in[4], d_in[7], d_in[10]};
  const void* bv[3] = {d_in[5], d_in[8], d_in[11]};
  const void* Wd = d_in[12];
  const void* bd = d_in[13];

  char* ws = (char*)d_ws;
  size_t o = 0;
  u16* Zq0 = (u16*)(ws+o); o += 16777216;           // [64][512][64] uint2 = 16MB each
  u16* Zq1 = (u16*)(ws+o); o += 16777216;
  u16* Zq2 = (u16*)(ws+o); o += 16777216;
  u16* xo0 = (u16*)(ws+o); o += 4096ull*512*2;      // 4MB
  u16* xo1 = (u16*)(ws+o); o += 4096ull*512*2;
  u16* xf  = (u16*)(ws+o); o += 65536ull*512*2;     // 64MB
  u16* embH = (u16*)(ws+o); o += 512ull*256*2;
  u16* WkT0 = (u16*)(ws+o); o += 2048ull*256*2;
  u16* WkT1 = (u16*)(ws+o); o += 2048ull*512*2;
  u16* WkT2 = (u16*)(ws+o); o += 2048ull*512*2;
  u16* WrT[3];
  for (int l=0;l<3;++l){ WrT[l] = (u16*)(ws+o); o += 2048ull*512*2; }
  u16* WdT = (u16*)(ws+o); o += 512ull*512*2;
  float* biasP[3];
  for (int l=0;l<3;++l){ biasP[l] = (float*)(ws+o); o += 2048*4; }
  float* bdP = (float*)(ws+o); o += 512*4;
  size_t ctrl0 = o;
  u32*  Hbase = (u32*)(ws+o); o += 3ull*65536*4;    // 3 layers x 2 bufs x [64][512] u32 = 768KB
  float* Cbase = (float*)(ws+o); o += 3ull*32768*4; // 384KB
  u32* dtypeflag = (u32*)(ws+o); o += 256;
  size_t need = o;
  if (ws_size < need) return;   // loud failure

  hipMemsetAsync(ws + ctrl0, 0, need - ctrl0, stream);

  detect_dtype<<<1,64,0,stream>>>(emb, dtypeflag);
  embconv<<<512,256,0,stream>>>(emb, embH, dtypeflag);
  transpose_bt<<<dim3(64,8) ,256,0,stream>>>(Wk[0], WkT0, 256, 2048, 1, dtypeflag);
  transpose_bt<<<dim3(64,16),256,0,stream>>>(Wk[1], WkT1, 512, 2048, 1, dtypeflag);
  transpose_bt<<<dim3(64,16),256,0,stream>>>(Wk[2], WkT2, 512, 2048, 1, dtypeflag);
  for (int l=0;l<3;++l)
    transpose_bt<<<dim3(64,16),256,0,stream>>>(Wr[l], WrT[l], 512, 2048, 1, dtypeflag);
  transpose_bt<<<dim3(16,16),256,0,stream>>>(Wd, WdT, 512, 512, 0, dtypeflag);
  for (int l=0;l<3;++l) bias_prep<<<8,256,0,stream>>>(bv[l], biasP[l], 2048, 1, dtypeflag);
  bias_prep<<<2,256,0,stream>>>(bd, bdP, 512, 0, dtypeflag);

  for (int d=0; d<18; ++d){
    int act0 = (d <= 15);
    int act1 = (d >= 1 && d <= 16);
    int act2 = (d >= 2);
    gemm3<<<dim3(32,16,3),256,0,stream>>>(xo0, xo1, WkT0, WkT1, WkT2,
                                          biasP[0], biasP[1], biasP[2],
                                          Zq0, Zq1, Zq2,
                                          tokens, embH, d*64, act0, act1, act2);
    lstm3<<<192,512,0,stream>>>((const uint2*)Zq0, (const uint2*)Zq1, (const uint2*)Zq2,
                                WrT[0], WrT[1], WrT[2],
                                lengths, xo0, xo1, xf, Hbase, Cbase, d);
  }
  gemm_bt<<<dim3(512,4),256,0,stream>>>(xf, WdT, bdP, d_out, 65536, 512, 512, dtypeflag);
}

// Round 8
// 4938.059 us; speedup vs baseline: 1.4340x; 1.4340x over previous
//
#include <hip/hip_runtime.h>
#include <stdint.h>

typedef unsigned short u16;
typedef unsigned int   u32;
typedef unsigned long long u64;
typedef _Float16 half8 __attribute__((ext_vector_type(8)));
typedef __attribute__((ext_vector_type(4))) float f32x4;

#define DEV static __device__ __forceinline__

DEV float bf2f(u16 u){ union{u32 i; float f;} v; v.i=((u32)u)<<16; return v.f; }
DEV u16 f2bf(float f){ u32 x=__float_as_uint(f); return (u16)((x + 0x7FFFu + ((x>>16)&1u))>>16); }
DEV u16 f2hu(float f){ _Float16 h = (_Float16)f; return *(u16*)&h; }
DEV float hu2f(u16 u){ _Float16 h = *(_Float16*)&u; return (float)h; }
DEV float sigm(float x){ return 1.0f/(1.0f+__expf(-x)); }
DEV float tanhr(float x){ float a=fabsf(x); float e=__expf(-2.0f*a); float t=(1.0f-e)/(1.0f+e); return x<0.0f? -t:t; }

typedef const __attribute__((address_space(1))) u32 gu32;
typedef __attribute__((address_space(3))) u32 lu32;
DEV void gload16(const void* g, void* l){
  __builtin_amdgcn_global_load_lds((gu32*)g, (lu32*)l, 16, 0, 0);
}
// coherent 4B store (write-through to coherence point), fire-and-forget
DEV void gstore4c(void* p, u32 v){
  asm volatile("global_store_dword %0, %1, off sc0 sc1" : : "v"(p), "v"(v) : "memory");
}

DEV u16 ld_h(const void* p, size_t i, int isbf){
  float f = isbf ? bf2f(((const u16*)p)[i]) : ((const float*)p)[i];
  return f2hu(f);
}

// -------- dtype detector: bf16 exponent-band statistics --------
__global__ void detect_dtype(const void* emb, u32* flag)
{
  const u16* p = (const u16*)emb;
  int i = threadIdx.x;
  u32 e0 = (p[i]    >> 7) & 0xFF;
  u32 e1 = (p[i+64] >> 7) & 0xFF;
  unsigned long long b0 = __ballot(e0 >= 0x60 && e0 <= 0x7E);
  unsigned long long b1 = __ballot(e1 >= 0x60 && e1 <= 0x7E);
  if (i == 0) *flag = (__popcll(b0) + __popcll(b1) > 96) ? 1u : 0u;
}

// -------- emb table -> fp16 (512x256) --------
__global__ __launch_bounds__(256) void embconv(const void* __restrict__ emb, u16* __restrict__ embH,
                                               const u32* __restrict__ flag)
{
  const int isbf = *flag;
  int i = blockIdx.x*256 + threadIdx.x;
  embH[i] = ld_h(emb, i, isbf);
}

// ------------- weight transpose (+ gate interleave): out[n'][k] = fp16(in[k][n]) -------------
__global__ __launch_bounds__(256) void transpose_bt(const void* __restrict__ in,
                                                    u16* __restrict__ out,
                                                    int K, int N, int perm,
                                                    const u32* __restrict__ flag)
{
  const int isbf = *flag;
  __shared__ u16 t[32][33];
  int nb = blockIdx.x*32, kb = blockIdx.y*32;
  int tx = threadIdx.x & 31, ty = threadIdx.x >> 5;   // 32 x 8
  #pragma unroll
  for (int i=0;i<4;++i){
    int kl = ty + i*8;
    t[kl][tx] = ld_h(in, (size_t)(kb+kl)*N + nb + tx, isbf);
  }
  __syncthreads();
  #pragma unroll
  for (int i=0;i<4;++i){
    int nl = ty + i*8;
    int n = nb + nl;
    int np = perm ? ((n & 511)*4 + (n >> 9)) : n;
    out[(size_t)np*K + kb + tx] = t[tx][nl];
  }
}

__global__ __launch_bounds__(256) void bias_prep(const void* __restrict__ in, float* __restrict__ out,
                                                 int N, int perm, const u32* __restrict__ flag)
{
  const int isbf = *flag;
  int n = blockIdx.x*256 + threadIdx.x;
  if (n < N){
    int np = perm ? ((n & 511)*4 + (n >> 9)) : n;
    out[np] = isbf ? bf2f(((const u16*)in)[n]) : ((const float*)in)[n];
  }
}

// ---------------- batched chunk GEMM (swapped operands): Zq[lt][u'][b] = packed 4-gate quads ----------------
// z=0: A gathered from embH via tokens (K=256). z=1,2: A = xo_prev chunk (K=512).
__global__ __launch_bounds__(256) void gemm3(
    const u16* __restrict__ A1, const u16* __restrict__ A2,
    const u16* __restrict__ BT0, const u16* __restrict__ BT1, const u16* __restrict__ BT2,
    const float* __restrict__ b0p, const float* __restrict__ b1p, const float* __restrict__ b2p,
    u16* __restrict__ C0, u16* __restrict__ C1, u16* __restrict__ C2,
    const int* __restrict__ tok, const u16* __restrict__ embH, int t0g,
    int act0, int act1, int act2)
{
  const int z = blockIdx.z;
  if (z==0 && !act0) return;
  if (z==1 && !act1) return;
  if (z==2 && !act2) return;
  const int K = (z==0) ? 256 : 512;
  const u16* BT = z==0?BT0 : z==1?BT1 : BT2;
  const float* bias = z==0?b0p : z==1?b1p : b2p;
  u16* C = z==0?C0 : z==1?C1 : C2;

  __shared__ u16 As[128*32];
  __shared__ u16 Bs[128*32];
  const int tid = threadIdx.x, lane = tid & 63, wid = tid >> 6;
  const int wr = wid >> 1, wc = wid & 1;
  const int m0 = blockIdx.x*128, n0 = blockIdx.y*128;
  const int r  = tid >> 2;
  const int ce = (tid & 3)*8;
  const u16 *a0, *a1;
  if (z == 0){
    int r0 = m0 + r;     int tt = t0g + (r0>>6); int bb = r0 & 63;
    a0 = embH + (size_t)tok[bb*1024 + tt]*256 + ce;
    int r1 = m0 + 64 + r; tt = t0g + (r1>>6); bb = r1 & 63;
    a1 = embH + (size_t)tok[bb*1024 + tt]*256 + ce;
  } else {
    const u16* A = (z==1) ? A1 : A2;
    a0 = A + (size_t)(m0 + r)*512 + ce;
    a1 = A + (size_t)(m0 + 64 + r)*512 + ce;
  }
  const u16* bp0 = BT + (size_t)(n0 + r)*K + ce;
  const u16* bp1 = BT + (size_t)(n0 + 64 + r)*K + ce;
  char* asw0 = (char*)As + (wid<<10);
  char* asw1 = (char*)As + 4096 + (wid<<10);
  char* bsw0 = (char*)Bs + (wid<<10);
  char* bsw1 = (char*)Bs + 4096 + (wid<<10);

  f32x4 acc[4][4];
  #pragma unroll
  for (int i=0;i<4;++i)
    #pragma unroll
    for (int j=0;j<4;++j) acc[i][j] = (f32x4){0.f,0.f,0.f,0.f};

  const int koff = (lane>>4)*8;
  for (int k0 = 0; k0 < K; k0 += 32){
    __syncthreads();
    gload16(a0 + k0, asw0);
    gload16(a1 + k0, asw1);
    gload16(bp0 + k0, bsw0);
    gload16(bp1 + k0, bsw1);
    __syncthreads();
    half8 af[4], bf[4];
    #pragma unroll
    for (int mt=0;mt<4;++mt) af[mt] = *(const half8*)(As + (wr*64 + mt*16 + (lane&15))*32 + koff);
    #pragma unroll
    for (int nt=0;nt<4;++nt) bf[nt] = *(const half8*)(Bs + (wc*64 + nt*16 + (lane&15))*32 + koff);
    // swapped: D rows = n' (register dim j -> gate), D cols = m (lane dim)
    #pragma unroll
    for (int mt=0;mt<4;++mt)
      #pragma unroll
      for (int nt=0;nt<4;++nt)
        acc[mt][nt] = __builtin_amdgcn_mfma_f32_16x16x32_f16(bf[nt], af[mt], acc[mt][nt], 0,0,0);
  }
  #pragma unroll
  for (int mt=0;mt<4;++mt){
    int m = m0 + wr*64 + mt*16 + (lane&15);
    int ltl = m >> 6, b = m & 63;
    #pragma unroll
    for (int nt=0;nt<4;++nt){
      int u = ((n0 + wc*64 + nt*16) >> 2) + (lane>>4);
      float4 bq = *(const float4*)(bias + u*4);
      u16 qo[4];
      qo[0] = f2hu(acc[mt][nt][0] + bq.x);
      qo[1] = f2hu(acc[mt][nt][1] + bq.y);
      qo[2] = f2hu(acc[mt][nt][2] + bq.z);
      qo[3] = f2hu(acc[mt][nt][3] + bq.w);
      ((uint2*)C)[(size_t)(ltl*512 + u)*64 + b] = *(uint2*)qo;
    }
  }
}

// ---------------- final logits GEMM (K=512, output permute t-major -> (B,T), dtype per flag) --------
__global__ __launch_bounds__(256) void gemm_bt(const u16* __restrict__ A, const u16* __restrict__ BT,
                                               const float* __restrict__ bias, void* __restrict__ C,
                                               int M, int N, int K, const u32* __restrict__ flag)
{
  __shared__ u16 As[128*32];
  __shared__ u16 Bs[128*32];
  const int tid = threadIdx.x, lane = tid & 63, wid = tid >> 6;
  const int wr = wid >> 1, wc = wid & 1;
  const int m0 = blockIdx.x*128, n0 = blockIdx.y*128;
  const int r  = tid >> 2;
  const int ce = (tid & 3)*8;
  const u16* a0 = A  + (size_t)(m0 + r)*K + ce;
  const u16* a1 = A  + (size_t)(m0 + 64 + r)*K + ce;
  const u16* b0 = BT + (size_t)(n0 + r)*K + ce;
  const u16* b1 = BT + (size_t)(n0 + 64 + r)*K + ce;
  char* asw0 = (char*)As + (wid<<10);
  char* asw1 = (char*)As + 4096 + (wid<<10);
  char* bsw0 = (char*)Bs + (wid<<10);
  char* bsw1 = (char*)Bs + 4096 + (wid<<10);

  f32x4 acc[4][4];
  #pragma unroll
  for (int i=0;i<4;++i)
    #pragma unroll
    for (int j=0;j<4;++j) acc[i][j] = (f32x4){0.f,0.f,0.f,0.f};

  const int koff = (lane>>4)*8;
  for (int k0 = 0; k0 < K; k0 += 32){
    __syncthreads();
    gload16(a0 + k0, asw0);
    gload16(a1 + k0, asw1);
    gload16(b0 + k0, bsw0);
    gload16(b1 + k0, bsw1);
    __syncthreads();
    half8 af[4], bf[4];
    #pragma unroll
    for (int mt=0;mt<4;++mt) af[mt] = *(const half8*)(As + (wr*64 + mt*16 + (lane&15))*32 + koff);
    #pragma unroll
    for (int nt=0;nt<4;++nt) bf[nt] = *(const half8*)(Bs + (wc*64 + nt*16 + (lane&15))*32 + koff);
    #pragma unroll
    for (int mt=0;mt<4;++mt)
      #pragma unroll
      for (int nt=0;nt<4;++nt)
        acc[mt][nt] = __builtin_amdgcn_mfma_f32_16x16x32_f16(af[mt], bf[nt], acc[mt][nt], 0,0,0);
  }
  const int wrf32 = (*flag == 0);
  #pragma unroll
  for (int mt=0;mt<4;++mt){
    #pragma unroll
    for (int nt=0;nt<4;++nt){
      int col = n0 + wc*64 + nt*16 + (lane&15);
      float bv = bias[col];
      #pragma unroll
      for (int j=0;j<4;++j){
        int row = m0 + wr*64 + mt*16 + ((lane>>4)<<2) + j;
        int orow = ((row & 63) << 10) | (row >> 6);
        float v = acc[mt][nt][j] + bv;
        if (wrf32) ((float*)C)[(size_t)orow*N + col] = v;
        else       ((u16*)C)[(size_t)orow*N + col] = f2bf(v);
      }
    }
  }
}

// ---------------- fused recurrence: 192 WGs = 3 layers x (4 batch-groups x 16 u-WGs) ----------------
// Tag-embedded H sync (r6 structure). This round's single change: Wr fragments are pinned in
// AGPRs via inline-asm MFMA with "a" operand constraint -- the allocator cannot rematerialize
// a global load into an AGPR-class vreg, so the per-step L2 weight re-fetch disappears.
__global__ __launch_bounds__(256,1) void lstm3(
    const uint2* __restrict__ Zq0, const uint2* __restrict__ Zq1, const uint2* __restrict__ Zq2,
    const u16* __restrict__ Wr0T, const u16* __restrict__ Wr1T, const u16* __restrict__ Wr2T,
    const int* __restrict__ lengths,
    u16* __restrict__ xo0, u16* __restrict__ xo1, u16* __restrict__ xf,
    u32* Hbase, float* Cbase, int d)
{
  __shared__ char Hs[16384];          // 16 rows x 1KB fp16, 16B-block XOR swizzle
  const int tid = threadIdx.x, lane = tid & 63, w = tid >> 6;
  const int layer = blockIdx.x >> 6;
  const int sub = blockIdx.x & 63;
  const int g = sub >> 4, i = sub & 15;
  const int c = d - layer;
  if (c < 0 || c > 15) return;
  const int t0 = c * 64;

  const uint2* Zq = layer==0?Zq0 : layer==1?Zq1 : Zq2;
  const u16* WrT  = layer==0?Wr0T : layer==1?Wr1T : Wr2T;
  u32* Hb0 = Hbase + (size_t)layer*65536;    // 2 bufs x [64][512] u32
  u32* Hb1 = Hb0 + 32768;
  float* Cg = Cbase + (size_t)layer*32768;

  const int q = lane >> 4, r15 = lane & 15, rsw = r15 & 7;
  const int bglob = g*16 + r15;
  const int mylen = lengths[bglob];
  const int u0 = i*32 + w*8 + q;
  const int u1 = u0 + 4;

  // Wr slice -> AGPR-resident fragments (128 AGPRs)
  half8 wreg[2][16];
  #pragma unroll
  for (int mt=0; mt<2; ++mt){
    const u16* wsrc = WrT + (size_t)(i*128 + (w*2+mt)*16 + r15)*512 + q*8;
    #pragma unroll
    for (int kk=0; kk<16; ++kk)
      wreg[mt][kk] = *(const half8*)(wsrc + kk*32);
  }
  float c0 = Cg[bglob*512 + u0];
  float c1 = Cg[bglob*512 + u1];

  // staging geometry: 4 chunks/thread, chunk = 8 u32 (32B tagged = 16B fp16)
  int chrow[4], chblk[4];
  #pragma unroll
  for (int jj=0;jj<4;++jj){ int ch = jj*256 + tid; chrow[jj] = ch>>6; chblk[jj] = ch & 63; }

  for (int lt = 0; lt < 64; ++lt){
    const int t = t0 + lt;
    u32* Hcur = (t & 1) ? Hb1 : Hb0;
    u32* Hnxt = (t & 1) ? Hb0 : Hb1;

    // Zx gate quads (plain cached loads, written by previous dispatch's gemm3)
    uint2 zqa = Zq[(size_t)(lt*512 + u0)*64 + bglob];
    uint2 zqb = Zq[(size_t)(lt*512 + u1)*64 + bglob];

    // ---- poll + stage: spin until each chunk's 8 tags == t, then extract -> LDS ----
    {
      const u32 tg = (u32)t;
      u32 pend = 0xF;
      do {
        #pragma unroll
        for (int jj=0;jj<4;++jj) if (pend & (1u<<jj)){
          const u64* src = (const u64*)(Hcur + (size_t)(g*16 + chrow[jj])*512 + chblk[jj]*8);
          u64 a0 = __hip_atomic_load(src+0, __ATOMIC_RELAXED, __HIP_MEMORY_SCOPE_AGENT);
          u64 a1 = __hip_atomic_load(src+1, __ATOMIC_RELAXED, __HIP_MEMORY_SCOPE_AGENT);
          u64 a2 = __hip_atomic_load(src+2, __ATOMIC_RELAXED, __HIP_MEMORY_SCOPE_AGENT);
          u64 a3 = __hip_atomic_load(src+3, __ATOMIC_RELAXED, __HIP_MEMORY_SCOPE_AGENT);
          bool ok = (((u32)a0)>>16)==tg && (((u32)(a0>>32))>>16)==tg
                 && (((u32)a1)>>16)==tg && (((u32)(a1>>32))>>16)==tg
                 && (((u32)a2)>>16)==tg && (((u32)(a2>>32))>>16)==tg
                 && (((u32)a3)>>16)==tg && (((u32)(a3>>32))>>16)==tg;
          if (ok){
            uint4 v;
            v.x = (((u32)a0)&0xFFFFu) | (((u32)(a0>>32))<<16);
            v.y = (((u32)a1)&0xFFFFu) | (((u32)(a1>>32))<<16);
            v.z = (((u32)a2)&0xFFFFu) | (((u32)(a2>>32))<<16);
            v.w = (((u32)a3)&0xFFFFu) | (((u32)(a3>>32))<<16);
            *(uint4*)(Hs + chrow[jj]*1024 + ((chblk[jj] ^ (chrow[jj] & 7))<<4)) = v;
            pend &= ~(1u<<jj);
          }
        }
      } while (pend);
    }
    __syncthreads();

    // ---- Z^T = Wr (AGPR) x H (LDS): lane = (b, u-part), regs = 4 gates ----
    f32x4 acc0 = {0.f,0.f,0.f,0.f}, acc1 = {0.f,0.f,0.f,0.f};
    #pragma unroll
    for (int kk=0;kk<16;++kk){
      half8 hf = *(const half8*)(Hs + r15*1024 + (((kk*4 + q) ^ rsw)<<4));
      asm("v_mfma_f32_16x16x32_f16 %0, %1, %2, %0"
          : "+v"(acc0) : "a"(wreg[0][kk]), "v"(hf));
      asm("v_mfma_f32_16x16x32_f16 %0, %1, %2, %0"
          : "+v"(acc1) : "a"(wreg[1][kk]), "v"(hf));
    }
    // inline-asm MFMA bypasses compiler hazard insertion: guard acc reads
    asm volatile("s_nop 7\n\ts_nop 7" : "+v"(acc0), "+v"(acc1));

    // ---- gates fully in-register ----
    const bool live = t < mylen;
    u16 hst0, hst1, xv0, xv1;
    {
      float zi = hu2f((u16)zqa.x)        + acc0[0];
      float zf = hu2f((u16)(zqa.x>>16))  + acc0[1];
      float zg = hu2f((u16)zqa.y)        + acc0[2];
      float zo = hu2f((u16)(zqa.y>>16))  + acc0[3];
      float ii = sigm(zi), ff = sigm(zf), gg = tanhr(zg), oo = sigm(zo);
      float cn = ff*c0 + ii*gg;
      float hn = oo*tanhr(cn);
      c0 = live ? cn : c0;
      int ub = u0*2;
      float hold = hu2f(*(const u16*)(Hs + r15*1024 + (((ub>>4) ^ rsw)<<4) + (ub & 15)));
      hst0 = f2hu(live ? hn : hold);
      xv0  = f2hu(live ? hn : 0.f);
    }
    {
      float zi = hu2f((u16)zqb.x)        + acc1[0];
      float zf = hu2f((u16)(zqb.x>>16))  + acc1[1];
      float zg = hu2f((u16)zqb.y)        + acc1[2];
      float zo = hu2f((u16)(zqb.y>>16))  + acc1[3];
      float ii = sigm(zi), ff = sigm(zf), gg = tanhr(zg), oo = sigm(zo);
      float cn = ff*c1 + ii*gg;
      float hn = oo*tanhr(cn);
      c1 = live ? cn : c1;
      int ub = u1*2;
      float hold = hu2f(*(const u16*)(Hs + r15*1024 + (((ub>>4) ^ rsw)<<4) + (ub & 15)));
      hst1 = f2hu(live ? hn : hold);
      xv1  = f2hu(live ? hn : 0.f);
    }
    // tagged h stores: fire-and-forget, no drain
    u32 s0 = (((u32)(t+1))<<16) | (u32)hst0;
    u32 s1 = (((u32)(t+1))<<16) | (u32)hst1;
    gstore4c(Hnxt + (size_t)bglob*512 + u0, s0);
    gstore4c(Hnxt + (size_t)bglob*512 + u1, s1);
    if (layer == 2){
      xf[((size_t)t*64 + bglob)*512 + u0] = xv0;
      xf[((size_t)t*64 + bglob)*512 + u1] = xv1;
    } else {
      u16* xo = layer ? xo1 : xo0;
      xo[((size_t)lt*64 + bglob)*512 + u0] = xv0;
      xo[((size_t)lt*64 + bglob)*512 + u1] = xv1;
    }
    __syncthreads();   // protect Hs from next iteration's staging overwrite
  }
  Cg[bglob*512 + u0] = c0;
  Cg[bglob*512 + u1] = c1;
}

// ---------------------------------- host ----------------------------------
extern "C" void kernel_launch(void* const* d_in, const int* in_sizes, int n_in,
                              void* d_out, int out_size, void* d_ws, size_t ws_size,
                              hipStream_t stream)
{
  const int* tokens  = (const int*)d_in[0];
  const int* lengths = (const int*)d_in[1];
  const void* emb    = d_in[2];
  const void* Wk[3] = {d_in[3], d_in[6], d_in[9]};
  const void* Wr[3] = {d_in[4], d_in[7], d_in[10]};
  const void* bv[3] = {d_in[5], d_in[8], d_in[11]};
  const void* Wd = d_in[12];
  const void* bd = d_in[13];

  char* ws = (char*)d_ws;
  size_t o = 0;
  u16* Zq0 = (u16*)(ws+o); o += 16777216;           // [64][512][64] uint2 = 16MB each
  u16* Zq1 = (u16*)(ws+o); o += 16777216;
  u16* Zq2 = (u16*)(ws+o); o += 16777216;
  u16* xo0 = (u16*)(ws+o); o += 4096ull*512*2;      // 4MB
  u16* xo1 = (u16*)(ws+o); o += 4096ull*512*2;
  u16* xf  = (u16*)(ws+o); o += 65536ull*512*2;     // 64MB
  u16* embH = (u16*)(ws+o); o += 512ull*256*2;
  u16* WkT0 = (u16*)(ws+o); o += 2048ull*256*2;
  u16* WkT1 = (u16*)(ws+o); o += 2048ull*512*2;
  u16* WkT2 = (u16*)(ws+o); o += 2048ull*512*2;
  u16* WrT[3];
  for (int l=0;l<3;++l){ WrT[l] = (u16*)(ws+o); o += 2048ull*512*2; }
  u16* WdT = (u16*)(ws+o); o += 512ull*512*2;
  float* biasP[3];
  for (int l=0;l<3;++l){ biasP[l] = (float*)(ws+o); o += 2048*4; }
  float* bdP = (float*)(ws+o); o += 512*4;
  size_t ctrl0 = o;
  u32*  Hbase = (u32*)(ws+o); o += 3ull*65536*4;    // 3 layers x 2 bufs x [64][512] u32 = 768KB
  float* Cbase = (float*)(ws+o); o += 3ull*32768*4; // 384KB
  u32* dtypeflag = (u32*)(ws+o); o += 256;
  size_t need = o;
  if (ws_size < need) return;   // loud failure

  hipMemsetAsync(ws + ctrl0, 0, need - ctrl0, stream);

  detect_dtype<<<1,64,0,stream>>>(emb, dtypeflag);
  embconv<<<512,256,0,stream>>>(emb, embH, dtypeflag);
  transpose_bt<<<dim3(64,8) ,256,0,stream>>>(Wk[0], WkT0, 256, 2048, 1, dtypeflag);
  transpose_bt<<<dim3(64,16),256,0,stream>>>(Wk[1], WkT1, 512, 2048, 1, dtypeflag);
  transpose_bt<<<dim3(64,16),256,0,stream>>>(Wk[2], WkT2, 512, 2048, 1, dtypeflag);
  for (int l=0;l<3;++l)
    transpose_bt<<<dim3(64,16),256,0,stream>>>(Wr[l], WrT[l], 512, 2048, 1, dtypeflag);
  transpose_bt<<<dim3(16,16),256,0,stream>>>(Wd, WdT, 512, 512, 0, dtypeflag);
  for (int l=0;l<3;++l) bias_prep<<<8,256,0,stream>>>(bv[l], biasP[l], 2048, 1, dtypeflag);
  bias_prep<<<2,256,0,stream>>>(bd, bdP, 512, 0, dtypeflag);

  for (int d=0; d<18; ++d){
    int act0 = (d <= 15);
    int act1 = (d >= 1 && d <= 16);
    int act2 = (d >= 2);
    gemm3<<<dim3(32,16,3),256,0,stream>>>(xo0, xo1, WkT0, WkT1, WkT2,
                                          biasP[0], biasP[1], biasP[2],
                                          Zq0, Zq1, Zq2,
                                          tokens, embH, d*64, act0, act1, act2);
    lstm3<<<192,256,0,stream>>>((const uint2*)Zq0, (const uint2*)Zq1, (const uint2*)Zq2,
                                WrT[0], WrT[1], WrT[2],
                                lengths, xo0, xo1, xf, Hbase, Cbase, d);
  }
  gemm_bt<<<dim3(512,4),256,0,stream>>>(xf, WdT, bdP, d_out, 65536, 512, 512, dtypeflag);
}

// Round 11
// 4174.359 us; speedup vs baseline: 1.6963x; 1.1830x over previous
//
#include <hip/hip_runtime.h>
#include <stdint.h>

typedef unsigned short u16;
typedef unsigned int   u32;
typedef unsigned long long u64;
typedef _Float16 half8 __attribute__((ext_vector_type(8)));
typedef __attribute__((ext_vector_type(4))) float f32x4;

#define DEV static __device__ __forceinline__

DEV float bf2f(u16 u){ union{u32 i; float f;} v; v.i=((u32)u)<<16; return v.f; }
DEV u16 f2bf(float f){ u32 x=__float_as_uint(f); return (u16)((x + 0x7FFFu + ((x>>16)&1u))>>16); }
DEV u16 f2hu(float f){ _Float16 h = (_Float16)f; return *(u16*)&h; }
DEV float hu2f(u16 u){ _Float16 h = *(_Float16*)&u; return (float)h; }
DEV float sigm(float x){ return 1.0f/(1.0f+__expf(-x)); }
DEV float tanhr(float x){ float a=fabsf(x); float e=__expf(-2.0f*a); float t=(1.0f-e)/(1.0f+e); return x<0.0f? -t:t; }

typedef const __attribute__((address_space(1))) u32 gu32;
typedef __attribute__((address_space(3))) u32 lu32;
DEV void gload16(const void* g, void* l){
  __builtin_amdgcn_global_load_lds((gu32*)g, (lu32*)l, 16, 0, 0);
}
// MALL-coherent 4B store (write-through to coherence point), fire-and-forget
DEV void gstore4c(void* p, u32 v){
  asm volatile("global_store_dword %0, %1, off sc0 sc1" : : "v"(p), "v"(v) : "memory");
}

DEV u16 ld_h(const void* p, size_t i, int isbf){
  float f = isbf ? bf2f(((const u16*)p)[i]) : ((const float*)p)[i];
  return f2hu(f);
}

// -------- dtype detector: bf16 exponent-band statistics --------
__global__ void detect_dtype(const void* emb, u32* flag)
{
  const u16* p = (const u16*)emb;
  int i = threadIdx.x;
  u32 e0 = (p[i]    >> 7) & 0xFF;
  u32 e1 = (p[i+64] >> 7) & 0xFF;
  unsigned long long b0 = __ballot(e0 >= 0x60 && e0 <= 0x7E);
  unsigned long long b1 = __ballot(e1 >= 0x60 && e1 <= 0x7E);
  if (i == 0) *flag = (__popcll(b0) + __popcll(b1) > 96) ? 1u : 0u;
}

// -------- emb table -> fp16 (512x256) --------
__global__ __launch_bounds__(256) void embconv(const void* __restrict__ emb, u16* __restrict__ embH,
                                               const u32* __restrict__ flag)
{
  const int isbf = *flag;
  int i = blockIdx.x*256 + threadIdx.x;
  embH[i] = ld_h(emb, i, isbf);
}

// ------------- weight transpose (+ gate interleave): out[n'][k] = fp16(in[k][n]) -------------
__global__ __launch_bounds__(256) void transpose_bt(const void* __restrict__ in,
                                                    u16* __restrict__ out,
                                                    int K, int N, int perm,
                                                    const u32* __restrict__ flag)
{
  const int isbf = *flag;
  __shared__ u16 t[32][33];
  int nb = blockIdx.x*32, kb = blockIdx.y*32;
  int tx = threadIdx.x & 31, ty = threadIdx.x >> 5;   // 32 x 8
  #pragma unroll
  for (int i=0;i<4;++i){
    int kl = ty + i*8;
    t[kl][tx] = ld_h(in, (size_t)(kb+kl)*N + nb + tx, isbf);
  }
  __syncthreads();
  #pragma unroll
  for (int i=0;i<4;++i){
    int nl = ty + i*8;
    int n = nb + nl;
    int np = perm ? ((n & 511)*4 + (n >> 9)) : n;
    out[(size_t)np*K + kb + tx] = t[tx][nl];
  }
}

__global__ __launch_bounds__(256) void bias_prep(const void* __restrict__ in, float* __restrict__ out,
                                                 int N, int perm, const u32* __restrict__ flag)
{
  const int isbf = *flag;
  int n = blockIdx.x*256 + threadIdx.x;
  if (n < N){
    int np = perm ? ((n & 511)*4 + (n >> 9)) : n;
    out[np] = isbf ? bf2f(((const u16*)in)[n]) : ((const float*)in)[n];
  }
}

// ---------------- batched chunk GEMM (swapped operands): Zq[lt][u'][b] = packed 4-gate quads ----------------
__global__ __launch_bounds__(256) void gemm3(
    const u16* __restrict__ A1, const u16* __restrict__ A2,
    const u16* __restrict__ BT0, const u16* __restrict__ BT1, const u16* __restrict__ BT2,
    const float* __restrict__ b0p, const float* __restrict__ b1p, const float* __restrict__ b2p,
    u16* __restrict__ C0, u16* __restrict__ C1, u16* __restrict__ C2,
    const int* __restrict__ tok, const u16* __restrict__ embH, int t0g,
    int act0, int act1, int act2)
{
  const int z = blockIdx.z;
  if (z==0 && !act0) return;
  if (z==1 && !act1) return;
  if (z==2 && !act2) return;
  const int K = (z==0) ? 256 : 512;
  const u16* BT = z==0?BT0 : z==1?BT1 : BT2;
  const float* bias = z==0?b0p : z==1?b1p : b2p;
  u16* C = z==0?C0 : z==1?C1 : C2;

  __shared__ u16 As[128*32];
  __shared__ u16 Bs[128*32];
  const int tid = threadIdx.x, lane = tid & 63, wid = tid >> 6;
  const int wr = wid >> 1, wc = wid & 1;
  const int m0 = blockIdx.x*128, n0 = blockIdx.y*128;
  const int r  = tid >> 2;
  const int ce = (tid & 3)*8;
  const u16 *a0, *a1;
  if (z == 0){
    int r0 = m0 + r;     int tt = t0g + (r0>>6); int bb = r0 & 63;
    a0 = embH + (size_t)tok[bb*1024 + tt]*256 + ce;
    int r1 = m0 + 64 + r; tt = t0g + (r1>>6); bb = r1 & 63;
    a1 = embH + (size_t)tok[bb*1024 + tt]*256 + ce;
  } else {
    const u16* A = (z==1) ? A1 : A2;
    a0 = A + (size_t)(m0 + r)*512 + ce;
    a1 = A + (size_t)(m0 + 64 + r)*512 + ce;
  }
  const u16* bp0 = BT + (size_t)(n0 + r)*K + ce;
  const u16* bp1 = BT + (size_t)(n0 + 64 + r)*K + ce;
  char* asw0 = (char*)As + (wid<<10);
  char* asw1 = (char*)As + 4096 + (wid<<10);
  char* bsw0 = (char*)Bs + (wid<<10);
  char* bsw1 = (char*)Bs + 4096 + (wid<<10);

  f32x4 acc[4][4];
  #pragma unroll
  for (int i=0;i<4;++i)
    #pragma unroll
    for (int j=0;j<4;++j) acc[i][j] = (f32x4){0.f,0.f,0.f,0.f};

  const int koff = (lane>>4)*8;
  for (int k0 = 0; k0 < K; k0 += 32){
    __syncthreads();
    gload16(a0 + k0, asw0);
    gload16(a1 + k0, asw1);
    gload16(bp0 + k0, bsw0);
    gload16(bp1 + k0, bsw1);
    __syncthreads();
    half8 af[4], bf[4];
    #pragma unroll
    for (int mt=0;mt<4;++mt) af[mt] = *(const half8*)(As + (wr*64 + mt*16 + (lane&15))*32 + koff);
    #pragma unroll
    for (int nt=0;nt<4;++nt) bf[nt] = *(const half8*)(Bs + (wc*64 + nt*16 + (lane&15))*32 + koff);
    // swapped: D rows = n' (register dim j -> gate), D cols = m (lane dim)
    #pragma unroll
    for (int mt=0;mt<4;++mt)
      #pragma unroll
      for (int nt=0;nt<4;++nt)
        acc[mt][nt] = __builtin_amdgcn_mfma_f32_16x16x32_f16(bf[nt], af[mt], acc[mt][nt], 0,0,0);
  }
  #pragma unroll
  for (int mt=0;mt<4;++mt){
    int m = m0 + wr*64 + mt*16 + (lane&15);
    int ltl = m >> 6, b = m & 63;
    #pragma unroll
    for (int nt=0;nt<4;++nt){
      int u = ((n0 + wc*64 + nt*16) >> 2) + (lane>>4);
      float4 bq = *(const float4*)(bias + u*4);
      u16 qo[4];
      qo[0] = f2hu(acc[mt][nt][0] + bq.x);
      qo[1] = f2hu(acc[mt][nt][1] + bq.y);
      qo[2] = f2hu(acc[mt][nt][2] + bq.z);
      qo[3] = f2hu(acc[mt][nt][3] + bq.w);
      ((uint2*)C)[(size_t)(ltl*512 + u)*64 + b] = *(uint2*)qo;
    }
  }
}

// ---------------- final logits GEMM (K=512, output permute t-major -> (B,T), dtype per flag) --------
__global__ __launch_bounds__(256) void gemm_bt(const u16* __restrict__ A, const u16* __restrict__ BT,
                                               const float* __restrict__ bias, void* __restrict__ C,
                                               int M, int N, int K, const u32* __restrict__ flag)
{
  __shared__ u16 As[128*32];
  __shared__ u16 Bs[128*32];
  const int tid = threadIdx.x, lane = tid & 63, wid = tid >> 6;
  const int wr = wid >> 1, wc = wid & 1;
  const int m0 = blockIdx.x*128, n0 = blockIdx.y*128;
  const int r  = tid >> 2;
  const int ce = (tid & 3)*8;
  const u16* a0 = A  + (size_t)(m0 + r)*K + ce;
  const u16* a1 = A  + (size_t)(m0 + 64 + r)*K + ce;
  const u16* b0 = BT + (size_t)(n0 + r)*K + ce;
  const u16* b1 = BT + (size_t)(n0 + 64 + r)*K + ce;
  char* asw0 = (char*)As + (wid<<10);
  char* asw1 = (char*)As + 4096 + (wid<<10);
  char* bsw0 = (char*)Bs + (wid<<10);
  char* bsw1 = (char*)Bs + 4096 + (wid<<10);

  f32x4 acc[4][4];
  #pragma unroll
  for (int i=0;i<4;++i)
    #pragma unroll
    for (int j=0;j<4;++j) acc[i][j] = (f32x4){0.f,0.f,0.f,0.f};

  const int koff = (lane>>4)*8;
  for (int k0 = 0; k0 < K; k0 += 32){
    __syncthreads();
    gload16(a0 + k0, asw0);
    gload16(a1 + k0, asw1);
    gload16(b0 + k0, bsw0);
    gload16(b1 + k0, bsw1);
    __syncthreads();
    half8 af[4], bf[4];
    #pragma unroll
    for (int mt=0;mt<4;++mt) af[mt] = *(const half8*)(As + (wr*64 + mt*16 + (lane&15))*32 + koff);
    #pragma unroll
    for (int nt=0;nt<4;++nt) bf[nt] = *(const half8*)(Bs + (wc*64 + nt*16 + (lane&15))*32 + koff);
    #pragma unroll
    for (int mt=0;mt<4;++mt)
      #pragma unroll
      for (int nt=0;nt<4;++nt)
        acc[mt][nt] = __builtin_amdgcn_mfma_f32_16x16x32_f16(af[mt], bf[nt], acc[mt][nt], 0,0,0);
  }
  const int wrf32 = (*flag == 0);
  #pragma unroll
  for (int mt=0;mt<4;++mt){
    #pragma unroll
    for (int nt=0;nt<4;++nt){
      int col = n0 + wc*64 + nt*16 + (lane&15);
      float bv = bias[col];
      #pragma unroll
      for (int j=0;j<4;++j){
        int row = m0 + wr*64 + mt*16 + ((lane>>4)<<2) + j;
        int orow = ((row & 63) << 10) | (row >> 6);
        float v = acc[mt][nt][j] + bv;
        if (wrf32) ((float*)C)[(size_t)orow*N + col] = v;
        else       ((u16*)C)[(size_t)orow*N + col] = f2bf(v);
      }
    }
  }
}

// ---------------- fused recurrence: 192 WGs = 3 layers x (4 batch-groups x 16 u-WGs) ----------------
// Tag-embedded H sync (r6/r8 structure). Round 11 changes vs r8:
//  (1) ONE-SHOT poll: all 8 dwordx4 chunk loads in a single asm block with a single
//      vmcnt(0) -- catch latency ~1 MALL RT instead of 4 serial RTs.
//  (2) double-buffered Hs LDS -> no trailing barrier (1 barrier/step).
__global__ __launch_bounds__(256,1) void lstm3(
    const uint2* __restrict__ Zq0, const uint2* __restrict__ Zq1, const uint2* __restrict__ Zq2,
    const u16* __restrict__ Wr0T, const u16* __restrict__ Wr1T, const u16* __restrict__ Wr2T,
    const int* __restrict__ lengths,
    u16* __restrict__ xo0, u16* __restrict__ xo1, u16* __restrict__ xf,
    u32* Hbase, float* Cbase, int d)
{
  __shared__ char Hs[2][16384];       // 16 rows x 1KB fp16 each, 16B-block XOR swizzle
  const int tid = threadIdx.x, lane = tid & 63, w = tid >> 6;
  const int layer = blockIdx.x >> 6;
  const int sub = blockIdx.x & 63;
  const int g = sub >> 4, i = sub & 15;
  const int c = d - layer;
  if (c < 0 || c > 15) return;
  const int t0 = c * 64;

  const uint2* Zq = layer==0?Zq0 : layer==1?Zq1 : Zq2;
  const u16* WrT  = layer==0?Wr0T : layer==1?Wr1T : Wr2T;
  u32* Hb0 = Hbase + (size_t)layer*65536;    // 2 bufs x [64][512] u32
  u32* Hb1 = Hb0 + 32768;
  float* Cg = Cbase + (size_t)layer*32768;

  const int q = lane >> 4, r15 = lane & 15, rsw = r15 & 7;
  const int bglob = g*16 + r15;
  const int mylen = lengths[bglob];
  const int u0 = i*32 + w*8 + q;
  const int u1 = u0 + 4;

  // Wr slice -> AGPR-resident fragments (128 AGPRs; "a"-constraint MFMA pins them)
  half8 wreg[2][16];
  #pragma unroll
  for (int mt=0; mt<2; ++mt){
    const u16* wsrc = WrT + (size_t)(i*128 + (w*2+mt)*16 + r15)*512 + q*8;
    #pragma unroll
    for (int kk=0; kk<16; ++kk)
      wreg[mt][kk] = *(const half8*)(wsrc + kk*32);
  }
  float c0 = Cg[bglob*512 + u0];
  float c1 = Cg[bglob*512 + u1];

  // staging geometry: 4 chunks/thread, chunk = 8 u32 (32B tagged = 16B fp16)
  int chrow[4], chblk[4];
  #pragma unroll
  for (int jj=0;jj<4;++jj){ int ch = jj*256 + tid; chrow[jj] = ch>>6; chblk[jj] = ch & 63; }

  for (int lt = 0; lt < 64; ++lt){
    const int t = t0 + lt;
    u32* Hcur = (t & 1) ? Hb1 : Hb0;
    u32* Hnxt = (t & 1) ? Hb0 : Hb1;
    char* Hsb = Hs[lt & 1];

    // Zx gate quads (plain cached loads, written by previous dispatch's gemm3)
    uint2 zqa = Zq[(size_t)(lt*512 + u0)*64 + bglob];
    uint2 zqb = Zq[(size_t)(lt*512 + u1)*64 + bglob];

    // ---- one-shot poll: 8 chunk loads, ONE vmcnt(0); all-32-tags-or-retry ----
    {
      const u32 tg = (u32)t;
      const u32* p0 = Hcur + (size_t)(g*16 + chrow[0])*512 + chblk[0]*8;
      const u32* p1 = Hcur + (size_t)(g*16 + chrow[1])*512 + chblk[1]*8;
      const u32* p2 = Hcur + (size_t)(g*16 + chrow[2])*512 + chblk[2]*8;
      const u32* p3 = Hcur + (size_t)(g*16 + chrow[3])*512 + chblk[3]*8;
      uint4 va0,vb0,va1,vb1,va2,vb2,va3,vb3;
      for (;;){
        asm volatile(
          "global_load_dwordx4 %0, %8, off sc0 sc1\n\t"
          "global_load_dwordx4 %1, %8, off offset:16 sc0 sc1\n\t"
          "global_load_dwordx4 %2, %9, off sc0 sc1\n\t"
          "global_load_dwordx4 %3, %9, off offset:16 sc0 sc1\n\t"
          "global_load_dwordx4 %4, %10, off sc0 sc1\n\t"
          "global_load_dwordx4 %5, %10, off offset:16 sc0 sc1\n\t"
          "global_load_dwordx4 %6, %11, off sc0 sc1\n\t"
          "global_load_dwordx4 %7, %11, off offset:16 sc0 sc1\n\t"
          "s_waitcnt vmcnt(0)"
          : "=&v"(va0), "=&v"(vb0), "=&v"(va1), "=&v"(vb1),
            "=&v"(va2), "=&v"(vb2), "=&v"(va3), "=&v"(vb3)
          : "v"(p0), "v"(p1), "v"(p2), "v"(p3)
          : "memory");
        bool ok = (va0.x>>16)==tg && (va0.y>>16)==tg && (va0.z>>16)==tg && (va0.w>>16)==tg
               && (vb0.x>>16)==tg && (vb0.y>>16)==tg && (vb0.z>>16)==tg && (vb0.w>>16)==tg
               && (va1.x>>16)==tg && (va1.y>>16)==tg && (va1.z>>16)==tg && (va1.w>>16)==tg
               && (vb1.x>>16)==tg && (vb1.y>>16)==tg && (vb1.z>>16)==tg && (vb1.w>>16)==tg
               && (va2.x>>16)==tg && (va2.y>>16)==tg && (va2.z>>16)==tg && (va2.w>>16)==tg
               && (vb2.x>>16)==tg && (vb2.y>>16)==tg && (vb2.z>>16)==tg && (vb2.w>>16)==tg
               && (va3.x>>16)==tg && (va3.y>>16)==tg && (va3.z>>16)==tg && (va3.w>>16)==tg
               && (vb3.x>>16)==tg && (vb3.y>>16)==tg && (vb3.z>>16)==tg && (vb3.w>>16)==tg;
        if (ok) break;
      }
      uint4 o;
      o.x=(va0.x&0xFFFFu)|(va0.y<<16); o.y=(va0.z&0xFFFFu)|(va0.w<<16);
      o.z=(vb0.x&0xFFFFu)|(vb0.y<<16); o.w=(vb0.z&0xFFFFu)|(vb0.w<<16);
      *(uint4*)(Hsb + chrow[0]*1024 + ((chblk[0] ^ (chrow[0] & 7))<<4)) = o;
      o.x=(va1.x&0xFFFFu)|(va1.y<<16); o.y=(va1.z&0xFFFFu)|(va1.w<<16);
      o.z=(vb1.x&0xFFFFu)|(vb1.y<<16); o.w=(vb1.z&0xFFFFu)|(vb1.w<<16);
      *(uint4*)(Hsb + chrow[1]*1024 + ((chblk[1] ^ (chrow[1] & 7))<<4)) = o;
      o.x=(va2.x&0xFFFFu)|(va2.y<<16); o.y=(va2.z&0xFFFFu)|(va2.w<<16);
      o.z=(vb2.x&0xFFFFu)|(vb2.y<<16); o.w=(vb2.z&0xFFFFu)|(vb2.w<<16);
      *(uint4*)(Hsb + chrow[2]*1024 + ((chblk[2] ^ (chrow[2] & 7))<<4)) = o;
      o.x=(va3.x&0xFFFFu)|(va3.y<<16); o.y=(va3.z&0xFFFFu)|(va3.w<<16);
      o.z=(vb3.x&0xFFFFu)|(vb3.y<<16); o.w=(vb3.z&0xFFFFu)|(vb3.w<<16);
      *(uint4*)(Hsb + chrow[3]*1024 + ((chblk[3] ^ (chrow[3] & 7))<<4)) = o;
    }
    __syncthreads();

    // ---- Z^T = Wr (AGPR) x H (LDS): lane = (b, u-part), regs = 4 gates ----
    f32x4 acc0 = {0.f,0.f,0.f,0.f}, acc1 = {0.f,0.f,0.f,0.f};
    #pragma unroll
    for (int kk=0;kk<16;++kk){
      half8 hf = *(const half8*)(Hsb + r15*1024 + (((kk*4 + q) ^ rsw)<<4));
      asm("v_mfma_f32_16x16x32_f16 %0, %1, %2, %0"
          : "+v"(acc0) : "a"(wreg[0][kk]), "v"(hf));
      asm("v_mfma_f32_16x16x32_f16 %0, %1, %2, %0"
          : "+v"(acc1) : "a"(wreg[1][kk]), "v"(hf));
    }
    asm volatile("s_nop 7\n\ts_nop 7" : "+v"(acc0), "+v"(acc1));

    // ---- gates fully in-register ----
    const bool live = t < mylen;
    u16 hst0, hst1, xv0, xv1;
    {
      float zi = hu2f((u16)zqa.x)        + acc0[0];
      float zf = hu2f((u16)(zqa.x>>16))  + acc0[1];
      float zg = hu2f((u16)zqa.y)        + acc0[2];
      float zo = hu2f((u16)(zqa.y>>16))  + acc0[3];
      float ii = sigm(zi), ff = sigm(zf), gg = tanhr(zg), oo = sigm(zo);
      float cn = ff*c0 + ii*gg;
      float hn = oo*tanhr(cn);
      c0 = live ? cn : c0;
      int ub = u0*2;
      float hold = hu2f(*(const u16*)(Hsb + r15*1024 + (((ub>>4) ^ rsw)<<4) + (ub & 15)));
      hst0 = f2hu(live ? hn : hold);
      xv0  = f2hu(live ? hn : 0.f);
    }
    {
      float zi = hu2f((u16)zqb.x)        + acc1[0];
      float zf = hu2f((u16)(zqb.x>>16))  + acc1[1];
      float zg = hu2f((u16)zqb.y)        + acc1[2];
      float zo = hu2f((u16)(zqb.y>>16))  + acc1[3];
      float ii = sigm(zi), ff = sigm(zf), gg = tanhr(zg), oo = sigm(zo);
      float cn = ff*c1 + ii*gg;
      float hn = oo*tanhr(cn);
      c1 = live ? cn : c1;
      int ub = u1*2;
      float hold = hu2f(*(const u16*)(Hsb + r15*1024 + (((ub>>4) ^ rsw)<<4) + (ub & 15)));
      hst1 = f2hu(live ? hn : hold);
      xv1  = f2hu(live ? hn : 0.f);
    }
    // tagged h stores: fire-and-forget to MALL
    u32 s0 = (((u32)(t+1))<<16) | (u32)hst0;
    u32 s1 = (((u32)(t+1))<<16) | (u32)hst1;
    gstore4c(Hnxt + (size_t)bglob*512 + u0, s0);
    gstore4c(Hnxt + (size_t)bglob*512 + u1, s1);
    if (layer == 2){
      xf[((size_t)t*64 + bglob)*512 + u0] = xv0;
      xf[((size_t)t*64 + bglob)*512 + u1] = xv1;
    } else {
      u16* xo = layer ? xo1 : xo0;
      xo[((size_t)lt*64 + bglob)*512 + u0] = xv0;
      xo[((size_t)lt*64 + bglob)*512 + u1] = xv1;
    }
    // no trailing barrier: next step stages into the other LDS buffer
  }
  Cg[bglob*512 + u0] = c0;
  Cg[bglob*512 + u1] = c1;
}

// ---------------------------------- host ----------------------------------
extern "C" void kernel_launch(void* const* d_in, const int* in_sizes, int n_in,
                              void* d_out, int out_size, void* d_ws, size_t ws_size,
                              hipStream_t stream)
{
  const int* tokens  = (const int*)d_in[0];
  const int* lengths = (const int*)d_in[1];
  const void* emb    = d_in[2];
  const void* Wk[3] = {d_in[3], d_in[6], d_in[9]};
  const void* Wr[3] = {d_in[4], d_in[7], d_in[10]};
  const void* bv[3] = {d_in[5], d_in[8], d_in[11]};
  const void* Wd = d_in[12];
  const void* bd = d_in[13];

  char* ws = (char*)d_ws;
  size_t o = 0;
  u16* Zq0 = (u16*)(ws+o); o += 16777216;           // [64][512][64] uint2 = 16MB each
  u16* Zq1 = (u16*)(ws+o); o += 16777216;
  u16* Zq2 = (u16*)(ws+o); o += 16777216;
  u16* xo0 = (u16*)(ws+o); o += 4096ull*512*2;      // 4MB
  u16* xo1 = (u16*)(ws+o); o += 4096ull*512*2;
  u16* xf  = (u16*)(ws+o); o += 65536ull*512*2;     // 64MB
  u16* embH = (u16*)(ws+o); o += 512ull*256*2;
  u16* WkT0 = (u16*)(ws+o); o += 2048ull*256*2;
  u16* WkT1 = (u16*)(ws+o); o += 2048ull*512*2;
  u16* WkT2 = (u16*)(ws+o); o += 2048ull*512*2;
  u16* WrT[3];
  for (int l=0;l<3;++l){ WrT[l] = (u16*)(ws+o); o += 2048ull*512*2; }
  u16* WdT = (u16*)(ws+o); o += 512ull*512*2;
  float* biasP[3];
  for (int l=0;l<3;++l){ biasP[l] = (float*)(ws+o); o += 2048*4; }
  float* bdP = (float*)(ws+o); o += 512*4;
  size_t ctrl0 = o;
  u32*  Hbase = (u32*)(ws+o); o += 3ull*65536*4;    // 3 layers x 2 bufs x [64][512] u32 = 768KB
  float* Cbase = (float*)(ws+o); o += 3ull*32768*4; // 384KB
  u32* dtypeflag = (u32*)(ws+o); o += 256;
  size_t need = o;
  if (ws_size < need) return;   // loud failure

  hipMemsetAsync(ws + ctrl0, 0, need - ctrl0, stream);

  detect_dtype<<<1,64,0,stream>>>(emb, dtypeflag);
  embconv<<<512,256,0,stream>>>(emb, embH, dtypeflag);
  transpose_bt<<<dim3(64,8) ,256,0,stream>>>(Wk[0], WkT0, 256, 2048, 1, dtypeflag);
  transpose_bt<<<dim3(64,16),256,0,stream>>>(Wk[1], WkT1, 512, 2048, 1, dtypeflag);
  transpose_bt<<<dim3(64,16),256,0,stream>>>(Wk[2], WkT2, 512, 2048, 1, dtypeflag);
  for (int l=0;l<3;++l)
    transpose_bt<<<dim3(64,16),256,0,stream>>>(Wr[l], WrT[l], 512, 2048, 1, dtypeflag);
  transpose_bt<<<dim3(16,16),256,0,stream>>>(Wd, WdT, 512, 512, 0, dtypeflag);
  for (int l=0;l<3;++l) bias_prep<<<8,256,0,stream>>>(bv[l], biasP[l], 2048, 1, dtypeflag);
  bias_prep<<<2,256,0,stream>>>(bd, bdP, 512, 0, dtypeflag);

  for (int d=0; d<18; ++d){
    int act0 = (d <= 15);
    int act1 = (d >= 1 && d <= 16);
    int act2 = (d >= 2);
    gemm3<<<dim3(32,16,3),256,0,stream>>>(xo0, xo1, WkT0, WkT1, WkT2,
                                          biasP[0], biasP[1], biasP[2],
                                          Zq0, Zq1, Zq2,
                                          tokens, embH, d*64, act0, act1, act2);
    lstm3<<<192,256,0,stream>>>((const uint2*)Zq0, (const uint2*)Zq1, (const uint2*)Zq2,
                                WrT[0], WrT[1], WrT[2],
                                lengths, xo0, xo1, xf, Hbase, Cbase, d);
  }
  gemm_bt<<<dim3(512,4),256,0,stream>>>(xf, WdT, bdP, d_out, 65536, 512, 512, dtypeflag);
}